// Round 3
// baseline (1653.065 us; speedup 1.0000x reference)
//
#include <hip/hip_runtime.h>
#include <math.h>

// PoseCDE: B=64, L=63, H=512, C=513, N_EVAL=10.
// Reduction (verified R1/R2, absmax 0): all RK4 stage times t in [0.1,1.0] ->
// ceil(t)-1==0 -> dXdt = (ts[:,2]-ts[:,1], 0,...,0) always. So
// f(z) = dt0[b] * tanh(relu(relu(z@Wf0+bf0)@Wf1+bf1) @ W0col + b0col),
// W0col[k][h] = Wout[k][h*513].
//
// R3 structure: weight-stationary teams. 8 teams x 32 WGs; team t owns batches
// [8t,8t+8); WG member m owns output cols [16m,16m+16) of ALL THREE weight
// matrices, preloaded to LDS once (3*16*516*4 = 97 KB). 108 sequential GEMMs
// run with per-team device-scope atomic barriers; activations (16 KB) exchange
// through ws. 1 WG/CU (LDS-forced) -> all 256 WGs resident.

#define OFF_W0COL 0        // 512*512
#define OFF_B0COL 262144   // 512
#define OFF_DT0   262656   // 64
#define OFF_CNT   262720   // 8 teams * 64 ints (separate cachelines)
#define OFF_Z     263232   // 64*512
#define OFF_K     296000   // 64*512
#define OFF_H1    328768   // 64*512
#define OFF_H2    361536   // 64*512
#define OFF_HI    394304   // 64*10*512

#define KPAD 516

__global__ void prep_kernel(const float* __restrict__ Wout,
                            const float* __restrict__ bout,
                            const float* __restrict__ ts,
                            float* __restrict__ ws) {
  int i = blockIdx.x * blockDim.x + threadIdx.x;
  if (i < 262144) {
    int k = i >> 9, h = i & 511;
    ws[OFF_W0COL + i] = Wout[(size_t)k * 262656 + (size_t)h * 513];
  } else if (i < 262656) {
    int h = i - 262144;
    ws[OFF_B0COL + h] = bout[(size_t)h * 513];
  } else if (i < 262720) {
    int b = i - 262656;
    ws[OFF_DT0 + b] = ts[b * 64 + 2] - ts[b * 64 + 1];
  } else if (i < 263232) {
    ws[OFF_CNT + (i - 262720)] = 0.f;        // barrier counters = 0
  } else if (i < 296000) {
    ws[OFF_Z + (i - 263232)] = 0.f;          // z0 = 0
  } else if (i < 328768) {
    int j = i - 296000;
    int b = j >> 9, n = j & 511;
    ws[OFF_HI + b * 5120 + n] = 0.f;         // h_i[:,0] = 0
  }
}

__global__ __launch_bounds__(256, 1) void cde_main(
    const float* __restrict__ Wf0, const float* __restrict__ bf0,
    const float* __restrict__ Wf1, const float* __restrict__ bf1,
    float* __restrict__ ws, float* __restrict__ out) {
  __shared__ __align__(16) float Wlds[3][16][KPAD];  // 99072 B
  __shared__ __align__(16) float Alds[8][KPAD];      // 16512 B
  __shared__ float part[256];                        // 1024 B

  const int t = threadIdx.x;
  const int team = blockIdx.x & 7;
  const int mem  = blockIdx.x >> 3;
  const int b0   = team * 8;    // global batch base
  const int col0 = mem * 16;    // global col base

  float* zg  = ws + OFF_Z;
  float* kg  = ws + OFF_K;
  float* h1g = ws + OFF_H1;
  float* h2g = ws + OFF_H2;
  float* hig = ws + OFF_HI;
  const float* w0c = ws + OFF_W0COL;
  int* cnt = ((int*)(ws + OFF_CNT)) + team * 64;

  // ---- preload weight slices (once) ----
  {
    int cl = t & 15;
    for (int kk = t >> 4; kk < 512; kk += 16) {
      Wlds[0][cl][kk] = Wf0[(size_t)kk * 512 + col0 + cl];
      Wlds[1][cl][kk] = Wf1[(size_t)kk * 512 + col0 + cl];
      Wlds[2][cl][kk] = w0c[(size_t)kk * 512 + col0 + cl];
    }
  }
  // per-output registers (threads 0..127: bl = t>>4, c = t&15)
  float bias0 = 0.f, bias1 = 0.f, bias2 = 0.f, dtv = 0.f;
  float zr = 0.f, accr = 0.f;
  if (t < 128) {
    int c = t & 15, bl = t >> 4;
    bias0 = bf0[col0 + c];
    bias1 = bf1[col0 + c];
    bias2 = ws[OFF_B0COL + col0 + c];
    dtv   = ws[OFF_DT0 + b0 + bl];
  }
  __syncthreads();

  const float hs = 0.1f;
  int phase = 0;

  for (int step = 0; step < 9; ++step) {
    for (int s = 0; s < 4; ++s) {
      const float cs = (s == 0) ? 0.f : ((s == 3) ? hs : 0.5f * hs);
      for (int sub = 0; sub < 3; ++sub) {
        // ---- stage activations into LDS: A[8][512] ----
        for (int i = t; i < 8 * 128; i += 256) {
          int bl = i >> 7;
          int n4 = (i & 127) << 2;
          const float* base;
          float4 v;
          if (sub == 0) {
            base = zg + (size_t)(b0 + bl) * 512 + n4;
            v = *(const float4*)base;
            if (cs != 0.f) {
              float4 k4 = *(const float4*)(kg + (size_t)(b0 + bl) * 512 + n4);
              v.x = fmaf(cs, k4.x, v.x); v.y = fmaf(cs, k4.y, v.y);
              v.z = fmaf(cs, k4.z, v.z); v.w = fmaf(cs, k4.w, v.w);
            }
          } else {
            const float* src = (sub == 1) ? h1g : h2g;
            v = *(const float4*)(src + (size_t)(b0 + bl) * 512 + n4);
          }
          *(float4*)&Alds[bl][n4] = v;
        }
        __syncthreads();

        // ---- GEMM partials: output o = t&127 (bl = o>>4, c = o&15), K-half = t>>7
        {
          int o = t & 127, kh = t >> 7;
          int bl = o >> 4, c = o & 15;
          const float4* wr = (const float4*)&Wlds[sub][c][kh * 256];
          const float4* ar = (const float4*)&Alds[bl][kh * 256];
          float a0 = 0.f, a1 = 0.f, a2 = 0.f, a3 = 0.f;
#pragma unroll 8
          for (int i = 0; i < 64; ++i) {
            float4 w = wr[i];
            float4 a = ar[i];
            a0 = fmaf(a.x, w.x, a0);
            a1 = fmaf(a.y, w.y, a1);
            a2 = fmaf(a.z, w.z, a2);
            a3 = fmaf(a.w, w.w, a3);
          }
          part[t] = (a0 + a1) + (a2 + a3);
        }
        __syncthreads();

        // ---- epilogue (threads 0..127) ----
        if (t < 128) {
          int bl = t >> 4, c = t & 15;
          int gb = b0 + bl, gc = col0 + c;
          float v = part[t] + part[t + 128];
          if (sub == 0) {
            h1g[(size_t)gb * 512 + gc] = fmaxf(v + bias0, 0.f);
          } else if (sub == 1) {
            h2g[(size_t)gb * 512 + gc] = fmaxf(v + bias1, 0.f);
          } else {
            float kv = dtv * tanhf(v + bias2);
            if (s < 3) {
              kg[(size_t)gb * 512 + gc] = kv;
              accr = (s == 0) ? kv : accr + 2.f * kv;
            } else {
              zr = zr + (hs / 6.f) * (accr + kv);
              zg[(size_t)gb * 512 + gc] = zr;
              hig[(size_t)gb * 5120 + (step + 1) * 512 + gc] = zr;
            }
          }
        }
        __syncthreads();  // drain stores (vmcnt 0) before release

        // ---- team barrier (device-scope, monotonic phase counter) ----
        ++phase;
        if (t == 0) {
          __hip_atomic_fetch_add(cnt, 1, __ATOMIC_RELEASE,
                                 __HIP_MEMORY_SCOPE_AGENT);
          const int target = 32 * phase;
          int guard = 0;
          while (__hip_atomic_load(cnt, __ATOMIC_RELAXED,
                                   __HIP_MEMORY_SCOPE_AGENT) < target) {
            if (++guard > 100000000) break;  // fail loud, not hang
          }
          (void)__hip_atomic_load(cnt, __ATOMIC_ACQUIRE,
                                  __HIP_MEMORY_SCOPE_AGENT);
        }
        __syncthreads();
      }
    }
  }

  // final hidden state -> out[3840 + b*512 + n]
  if (t < 128) {
    int bl = t >> 4, c = t & 15;
    out[3840 + (size_t)(b0 + bl) * 512 + col0 + c] = zr;
  }
}

// poses[b,s,:] = leaky_relu(h_i[b,s]@Wr1+br1, 0.1) @ Wr2 + br2
__global__ __launch_bounds__(128) void regressor_kernel(
    const float* __restrict__ hi, const float* __restrict__ Wr1,
    const float* __restrict__ br1, const float* __restrict__ Wr2,
    const float* __restrict__ br2, float* __restrict__ out) {
  int b = blockIdx.x / 10, s = blockIdx.x % 10;
  const float* hrow = hi + (size_t)b * 5120 + s * 512;
  int j = threadIdx.x;
  float acc = br1[j];
#pragma unroll 4
  for (int k = 0; k < 512; ++k) acc = fmaf(hrow[k], Wr1[k * 128 + j], acc);
  float hr = acc > 0.f ? acc : 0.1f * acc;
  __shared__ float sh[128];
  sh[j] = hr;
  __syncthreads();
  if (j < 6) {
    float p = br2[j];
#pragma unroll
    for (int k = 0; k < 128; ++k) p = fmaf(sh[k], Wr2[k * 6 + j], p);
    out[b * 60 + s * 6 + j] = p;
  }
}

extern "C" void kernel_launch(void* const* d_in, const int* in_sizes, int n_in,
                              void* d_out, int out_size, void* d_ws, size_t ws_size,
                              hipStream_t stream) {
  const float* ts   = (const float*)d_in[2];
  const float* Wf0  = (const float*)d_in[3];
  const float* bf0  = (const float*)d_in[4];
  const float* Wf1  = (const float*)d_in[5];
  const float* bf1  = (const float*)d_in[6];
  const float* Wout = (const float*)d_in[7];
  const float* bout = (const float*)d_in[8];
  const float* Wr1  = (const float*)d_in[9];
  const float* br1  = (const float*)d_in[10];
  const float* Wr2  = (const float*)d_in[11];
  const float* br2  = (const float*)d_in[12];
  float* out = (float*)d_out;
  float* ws  = (float*)d_ws;

  prep_kernel<<<(328768 + 255) / 256, 256, 0, stream>>>(Wout, bout, ts, ws);
  cde_main<<<256, 256, 0, stream>>>(Wf0, bf0, Wf1, bf1, ws, out);
  regressor_kernel<<<640, 128, 0, stream>>>(ws + OFF_HI, Wr1, br1, Wr2, br2, out);
}